// Round 2
// baseline (329.390 us; speedup 1.0000x reference)
//
#include <hip/hip_runtime.h>

#define I_LEN 1024
#define S_LEN 4096
#define CHUNKS 512      // k1a grid: s-chunks
#define ROWS 8          // s-rows per chunk (CHUNKS*ROWS == S_LEN)

typedef float f32x4 __attribute__((ext_vector_type(4)));

__device__ __forceinline__ float bf2f(unsigned int lo16) {
  unsigned int u = lo16 << 16;
  float f; __builtin_memcpy(&f, &u, 4); return f;
}
__device__ __forceinline__ unsigned int f2bf(float f) {
  unsigned int u; __builtin_memcpy(&u, &f, 4);
  return (u + 0x7FFFu + ((u >> 16) & 1u)) >> 16;  // RNE
}

// K1a: pure streaming pass. Block = 8 contiguous s-rows x all 1024 columns;
// thread = one column. Every wave load is 2 KB contiguous; every block streams
// a contiguous 256 KB span of m (fixes the 32KB-stride channel camping that
// held old K1 at 1.67 TB/s). Emits:
//   kvT[i][s]   packed bf16 (k<<16|v), column-major for K1b
//   part[ch][i][12]  q-numerator partials (8) + mask-count (1) + pad
//   mbytes[i][ch]    8 mask bits per chunk
// No LDS, no barriers.
__global__ __launch_bounds__(1024, 4) void msa_k1a(
    const float* __restrict__ m, const float* __restrict__ mask,
    const float* __restrict__ lng, const float* __restrict__ lnb,
    const float* __restrict__ Wk, const float* __restrict__ Wv,
    unsigned int* __restrict__ kvT, float* __restrict__ part,
    unsigned char* __restrict__ mbytes)
{
  const int i  = threadIdx.x;      // column
  const int ch = blockIdx.x;       // s-chunk
  const int s0 = ch * ROWS;

  // uniform scalars (SGPR-resident weights)
  float swk = 0.f, swv = 0.f, kb = 0.f, vb = 0.f;
#pragma unroll
  for (int c = 0; c < 8; ++c) {
    swk = fmaf(lng[c], Wk[c], swk);  swv = fmaf(lng[c], Wv[c], swv);
    kb  = fmaf(lnb[c], Wk[c], kb);   vb  = fmaf(lnb[c], Wv[c], vb);
  }

  float qnx[8] = {0,0,0,0,0,0,0,0};
  float qd = 0.f;
  unsigned int kvbuf[ROWS];
  unsigned int mb = 0;

#pragma unroll 2
  for (int j = 0; j < ROWS; ++j) {
    const int s = s0 + j;
    const float4* mp = (const float4*)(m + (size_t)(s * I_LEN + i) * 8);
    const float4 lo = mp[0], hi = mp[1];
    const float mk = mask[s * I_LEN + i];
    float x[8] = {lo.x, lo.y, lo.z, lo.w, hi.x, hi.y, hi.z, hi.w};
    float su = 0.f, s2 = 0.f;
#pragma unroll
    for (int c = 0; c < 8; ++c) { su += x[c]; s2 = fmaf(x[c], x[c], s2); }
    const float mu   = su * 0.125f;
    const float var  = s2 * 0.125f - mu * mu;
    const float rstd = rsqrtf(var + 1e-5f);
    float dk = 0.f, dv = 0.f;
#pragma unroll
    for (int c = 0; c < 8; ++c) {
      const float xg = x[c] * lng[c];          // gamma fold
      dk = fmaf(xg, Wk[c], dk);
      dv = fmaf(xg, Wv[c], dv);
      x[c] = xg;
    }
    const float kk  = fmaf(rstd, fmaf(-mu, swk, dk), kb);
    const float vv  = fmaf(rstd, fmaf(-mu, swv, dv), vb);
    const float mr  = mk * rstd;
    const float mmr = -mu * mr;
#pragma unroll
    for (int c = 0; c < 8; ++c)
      qnx[c] = fmaf(x[c], mr, fmaf(lng[c], mmr, qnx[c]));
    qd += mk;
    kvbuf[j] = (f2bf(kk) << 16) | f2bf(vv);
    mb |= (mk > 0.5f ? 1u : 0u) << j;
  }

  // kvT[i][s0..s0+7]: 32 B contiguous per thread (L2 assembles full lines)
  uint4* kp = (uint4*)(kvT + (size_t)i * S_LEN + s0);
  kp[0] = make_uint4(kvbuf[0], kvbuf[1], kvbuf[2], kvbuf[3]);
  kp[1] = make_uint4(kvbuf[4], kvbuf[5], kvbuf[6], kvbuf[7]);

  // part[ch][i][0..11]: 48 B contiguous per thread, wave-contiguous
  float4* pp = (float4*)(part + ((size_t)ch * I_LEN + i) * 12);
  pp[0] = make_float4(qnx[0], qnx[1], qnx[2], qnx[3]);
  pp[1] = make_float4(qnx[4], qnx[5], qnx[6], qnx[7]);
  pp[2] = make_float4(qd, 0.f, 0.f, 0.f);

  mbytes[(size_t)i * CHUNKS + ch] = (unsigned char)mb;
}

// K1b: one block per column. Reduce q-partials -> q heads -> softmax over s
// reading kvT column-contiguously (1 KB per wave load, L2/L3-hot).
__global__ __launch_bounds__(256) void msa_k1b(
    const float* __restrict__ lnb, const float* __restrict__ Wq,
    const unsigned int* __restrict__ kvT, const float* __restrict__ part,
    const unsigned char* __restrict__ mbytes, float* __restrict__ o_tab)
{
  __shared__ float red[4][16];
  __shared__ float qp_s[8];
  __shared__ float qtab[8];

  const int i    = blockIdx.x;
  const int t    = threadIdx.x;
  const int lane = t & 63;
  const int wave = t >> 6;

  // ---- phase 1: pooled-q reduction over 512 chunk-partials ----
  float v[9];
  {
    const float4* p0 = (const float4*)(part + ((size_t)t         * I_LEN + i) * 12);
    const float4* p1 = (const float4*)(part + ((size_t)(t + 256) * I_LEN + i) * 12);
    const float4 a0 = p0[0], a1 = p0[1], a2 = p0[2];
    const float4 b0 = p1[0], b1 = p1[1], b2 = p1[2];
    v[0] = a0.x + b0.x; v[1] = a0.y + b0.y; v[2] = a0.z + b0.z; v[3] = a0.w + b0.w;
    v[4] = a1.x + b1.x; v[5] = a1.y + b1.y; v[6] = a1.z + b1.z; v[7] = a1.w + b1.w;
    v[8] = a2.x + b2.x;
  }
#pragma unroll
  for (int q = 0; q < 9; ++q) {
    float x = v[q];
#pragma unroll
    for (int off = 1; off <= 32; off <<= 1) x += __shfl_xor(x, off, 64);
    if (lane == 0) red[wave][q] = x;
  }
  __syncthreads();
  if (t < 8) {
    const float d = red[0][8] + red[1][8] + red[2][8] + red[3][8];
    const float s = red[0][t] + red[1][t] + red[2][t] + red[3][t];
    qp_s[t] = (s + lnb[t] * d) / (d + 1e-5f);   // + beta*sum(mk), / (den+eps)
  }
  __syncthreads();
  if (t < 8) {
    float qv = 0.f;
#pragma unroll
    for (int c = 0; c < 8; ++c) qv = fmaf(qp_s[c], Wq[c * 8 + t], qv);
    qtab[t] = qv;                                // c_h^-0.5 == 1
  }
  __syncthreads();
  float qh[8];
#pragma unroll
  for (int h = 0; h < 8; ++h) qh[h] = qtab[h];

  // ---- phase 2: softmax sums over s (no max-subtraction; logits O(1)) ----
  float se[8] = {0,0,0,0,0,0,0,0};
  float sv[8] = {0,0,0,0,0,0,0,0};
#pragma unroll 4
  for (int j = 0; j < 16; ++j) {
    const int s = t + 256 * j;
    const unsigned int w = kvT[(size_t)i * S_LEN + s];
    const unsigned int mbit = (mbytes[(size_t)i * CHUNKS + (s >> 3)] >> (s & 7)) & 1u;
    const float kk = bf2f(w >> 16);
    const float vv = bf2f(w & 0xFFFFu);
    const float on = mbit ? 1.0f : 0.0f;
#pragma unroll
    for (int h = 0; h < 8; ++h) {
      const float e = __expf(qh[h] * kk) * on;
      se[h] += e;
      sv[h] = fmaf(e, vv, sv[h]);
    }
  }
#pragma unroll
  for (int q = 0; q < 16; ++q) {
    float x = (q < 8) ? se[q] : sv[q - 8];
#pragma unroll
    for (int off = 1; off <= 32; off <<= 1) x += __shfl_xor(x, off, 64);
    if (lane == 0) red[wave][q] = x;
  }
  __syncthreads();
  if (t < 8) {
    const float a = red[0][t]     + red[1][t]     + red[2][t]     + red[3][t];
    const float b = red[0][8 + t] + red[1][8 + t] + red[2][8 + t] + red[3][8 + t];
    o_tab[(size_t)i * 8 + t] = b / a;
  }
}

// K2: streaming gate+output pass (unchanged math). out-stores are NON-TEMPORAL
// (native ext_vector_type for the builtin): out is never re-read, and keeping
// its 128 MiB of dirty lines out of L3 preserves m (streamed in by K1a) so
// K2's m re-read L3-hits.
__global__ __launch_bounds__(256, 2) void msa_k2(
    const float* __restrict__ m,
    const float* __restrict__ lng, const float* __restrict__ lnb,
    const float* __restrict__ Wg, const float* __restrict__ bg,
    const float* __restrict__ Wo, const float* __restrict__ bo,
    const float* __restrict__ o_tab, float* __restrict__ out)
{
  const int tid = blockIdx.x * 256 + threadIdx.x;   // 524288 threads
  const int i = tid & (I_LEN - 1);

  // uniform derived vectors (SGPR-resident weights)
  float sgv[8], tbv[8];
#pragma unroll
  for (int h = 0; h < 8; ++h) {
    float s = 0.f, tb = bg[h];
#pragma unroll
    for (int c = 0; c < 8; ++c) {
      s  = fmaf(lng[c], Wg[c * 8 + h], s);
      tb = fmaf(lnb[c], Wg[c * 8 + h], tb);
    }
    sgv[h] = s; tbv[h] = tb;
  }

  const float4* op = (const float4*)(o_tab + i * 8);
  const float4 o1 = op[0], o2 = op[1];
  const float A[8] = {o1.x, o1.y, o1.z, o1.w, o2.x, o2.y, o2.z, o2.w};

#pragma unroll 2
  for (int q = 0; q < 8; ++q) {
    const size_t p = (size_t)tid + (size_t)q * 524288;
    const float4* mp = (const float4*)(m + p * 8);
    const float4 lo = mp[0], hi = mp[1];
    float x[8] = {lo.x, lo.y, lo.z, lo.w, hi.x, hi.y, hi.z, hi.w};
    float su = 0.f, s2 = 0.f;
#pragma unroll
    for (int c = 0; c < 8; ++c) { su += x[c]; s2 = fmaf(x[c], x[c], s2); }
    const float mu   = su * 0.125f;
    const float var  = s2 * 0.125f - mu * mu;
    const float rstd = rsqrtf(var + 1e-5f);
#pragma unroll
    for (int c = 0; c < 8; ++c) x[c] *= lng[c];
    float acc[8];
#pragma unroll
    for (int c = 0; c < 8; ++c) acc[c] = bo[c];
#pragma unroll
    for (int h = 0; h < 8; ++h) {
      float d = 0.f;
#pragma unroll
      for (int c = 0; c < 8; ++c) d = fmaf(x[c], Wg[c * 8 + h], d);
      const float gl = fmaf(rstd, fmaf(-mu, sgv[h], d), tbv[h]);
      const float gv = A[h] / (1.0f + __expf(-gl));
#pragma unroll
      for (int c = 0; c < 8; ++c) acc[c] = fmaf(gv, Wo[h * 8 + c], acc[c]);
    }
    f32x4* outp = (f32x4*)(out + p * 8);
    f32x4 r0 = {acc[0], acc[1], acc[2], acc[3]};
    f32x4 r1 = {acc[4], acc[5], acc[6], acc[7]};
    __builtin_nontemporal_store(r0, outp);
    __builtin_nontemporal_store(r1, outp + 1);
  }
}

extern "C" void kernel_launch(void* const* d_in, const int* in_sizes, int n_in,
                              void* d_out, int out_size, void* d_ws, size_t ws_size,
                              hipStream_t stream) {
  const float* m    = (const float*)d_in[0];
  const float* mask = (const float*)d_in[1];
  const float* lng  = (const float*)d_in[2];
  const float* lnb  = (const float*)d_in[3];
  const float* Wq   = (const float*)d_in[4];
  const float* Wk   = (const float*)d_in[5];
  const float* Wv   = (const float*)d_in[6];
  const float* Wg   = (const float*)d_in[7];
  const float* bg   = (const float*)d_in[8];
  const float* Wo   = (const float*)d_in[9];
  const float* bo   = (const float*)d_in[10];
  float* out = (float*)d_out;

  // ws layout: o_tab 32KB @0 | kvT 16MiB @1MiB | part 25.2MB @20MiB | mbytes 512KB @48MiB
  char* ws = (char*)d_ws;
  float*         o_tab  = (float*)ws;
  unsigned int*  kvT    = (unsigned int*)(ws + ((size_t)1 << 20));
  float*         part   = (float*)(ws + ((size_t)20 << 20));
  unsigned char* mbytes = (unsigned char*)(ws + ((size_t)48 << 20));

  hipLaunchKernelGGL(msa_k1a, dim3(CHUNKS), dim3(1024), 0, stream,
                     m, mask, lng, lnb, Wk, Wv, kvT, part, mbytes);
  hipLaunchKernelGGL(msa_k1b, dim3(I_LEN), dim3(256), 0, stream,
                     lnb, Wq, kvT, part, mbytes, o_tab);
  hipLaunchKernelGGL(msa_k2, dim3(2048), dim3(256), 0, stream,
                     m, lng, lnb, Wg, bg, Wo, bo, o_tab, out);
}